// Round 20
// baseline (27.173 us; speedup 1.0000x reference)
//
#include <hip/hip_runtime.h>
#include <hip/hip_bf16.h>

typedef __attribute__((ext_vector_type(4))) float f32x4;
typedef __attribute__((ext_vector_type(8))) short s16x8;
typedef unsigned int u32;

#define DHEAD 128
#define KVB 32             // kv rows per tile
#define BLKQ 64            // q-rows per block = 2 qslot-waves x 32 rows
#define NGRP 4             // in-block kv groups
#define TILB 8192          // bytes per fragment-ordered 32x128 bf16 tile
#define LDSZ 133120        // staging 128KB (also merge: 128KB P + 1KB lred)

__device__ __forceinline__ short f2bf(float x) {
    __hip_bfloat16 h = __float2bfloat16(x);
    return *reinterpret_cast<short*>(&h);
}

// Rewrite K,V (f32 row-major) -> bf16 MFMA-FRAGMENT order, 32-row tiles
// (identical to R16/R19):
//  K tile t: unit u=(s*4+kk)*64+lane, lane=(g,qi): K[t*32+16s+qi][kk*32+g*8+e]
//  V tile t: unit u=dg*64+lane: e<4: V[t*32+g*4+e][dg*16+qi]; e>=4: +16 rows
__global__ __launch_bounds__(256)
void prep_frag(const float* __restrict__ K, const float* __restrict__ V,
               const int* __restrict__ VL,
               short* __restrict__ Kz, short* __restrict__ Vz, int m, int NT, int nkf) {
    const int i = blockIdx.x * 256 + threadIdx.x;
    if (i < nkf) {
        const int lane = i & 63;
        const int kk   = (i >> 6) & 3;
        const int s    = (i >> 8) & 1;
        const int rest = i >> 9;
        const int t = rest % NT, b = rest / NT;
        if (t * KVB >= VL[b]) return;
        const int qi = lane & 15, g = lane >> 4;
        const float* src = K + (size_t)(b * m + t * KVB + 16 * s + qi) * DHEAD + kk * 32 + g * 8;
        f32x4 a = *reinterpret_cast<const f32x4*>(src);
        f32x4 c = *reinterpret_cast<const f32x4*>(src + 4);
        s16x8 o;
        #pragma unroll
        for (int j = 0; j < 4; ++j) { o[j] = f2bf(a[j]); o[4 + j] = f2bf(c[j]); }
        *reinterpret_cast<s16x8*>(Kz + (size_t)i * 8) = o;
    } else {
        const int j = i - nkf;
        if (j < nkf) {
            const int lane = j & 63;
            const int dg   = (j >> 6) & 7;
            const int rest = j >> 9;
            const int t = rest % NT, b = rest / NT;
            if (t * KVB >= VL[b]) return;
            const int qi = lane & 15, g = lane >> 4;
            const float* vb = V + (size_t)(b * m + t * KVB + g * 4) * DHEAD + dg * 16 + qi;
            s16x8 o;
            #pragma unroll
            for (int r = 0; r < 4; ++r) {
                o[r]     = f2bf(vb[(size_t)r * DHEAD]);
                o[4 + r] = f2bf(vb[(size_t)(16 + r) * DHEAD]);
            }
            *reinterpret_cast<s16x8*>(Vz + (size_t)j * 8) = o;
        }
    }
}

// R16's in-block kv-split attention, LDS-traffic-halved: each wave owns
// 32 q-rows as TWO independent 16-row MFMA streams (qf0/qf1, pa0/pa1) so one
// kf/vf ds_read_b128 feeds two MFMAs. R16 was LDS-BW bound (~256KB reads/
// CU-iter = 2000cy vs 312cy MFMA; 4 qslot waves re-read identical fragments).
// 8 waves = 2 qslot-waves x 4 kv-groups, group-private dbuf staging, fixed-
// origin softmax, parallel in-LDS merge (R19 epilogue, 4 virtual qslots).
__global__ __launch_bounds__(512, 2)
void attn_fwd(const float* __restrict__ Q, const short* __restrict__ Kz,
              const short* __restrict__ Vz, const int* __restrict__ VL,
              float* __restrict__ O, int B, int n, int NT) {
    extern __shared__ char lds[];   // LDSZ bytes

    const int tid   = threadIdx.x;
    const int lane  = tid & 63;
    const int wid   = tid >> 6;     // 0..7
    const int qslot = wid & 1;      // 32-row q sub-tile
    const int grp   = wid >> 1;     // kv group 0..3
    const int gl    = lane >> 4;    // 0..3
    const int qi    = lane & 15;

    // XCD-pinned decode: 2 batches/XCD -> bf16 KV stream L2-resident.
    const int nq = n / BLKQ;        // 16
    int b, qt;
    if ((B & 7) == 0) {
        const int xcd = blockIdx.x & 7;
        const int sub = blockIdx.x >> 3;
        const int bpx = B >> 3;
        b  = xcd * bpx + (sub % bpx);
        qt = sub / bpx;
    } else {
        b = blockIdx.x / nq; qt = blockIdx.x % nq;
    }

    const int vl = VL[b];
    const int nt = (vl + KVB - 1) / KVB;        // 1..32
    const int IT = (nt + NGRP - 1) / NGRP;      // uniform per-group iterations
    const int rowbase = b * n + qt * BLKQ + qslot * 32;   // this wave's 32 rows

    // ---- Q fragments for both 16-row halves, pre-scaled ----
    const float qsc = 0.08838834764831845f * 1.4426950408889634f;
    s16x8 qf0[4], qf1[4];
    {
        const float* qp0 = Q + (size_t)(rowbase + qi) * DHEAD + gl * 8;
        const float* qp1 = qp0 + 16 * DHEAD;
        #pragma unroll
        for (int kk = 0; kk < 4; ++kk) {
            f32x4 a0 = *reinterpret_cast<const f32x4*>(qp0 + kk * 32);
            f32x4 c0 = *reinterpret_cast<const f32x4*>(qp0 + kk * 32 + 4);
            f32x4 a1 = *reinterpret_cast<const f32x4*>(qp1 + kk * 32);
            f32x4 c1 = *reinterpret_cast<const f32x4*>(qp1 + kk * 32 + 4);
            s16x8 s0, s1;
            #pragma unroll
            for (int j = 0; j < 4; ++j) {
                s0[j] = f2bf(a0[j] * qsc); s0[4 + j] = f2bf(c0[j] * qsc);
                s1[j] = f2bf(a1[j] * qsc); s1[4 + j] = f2bf(c1[j] * qsc);
            }
            qf0[kk] = s0; qf1[kk] = s1;
        }
    }

    const char* KzB = (const char*)Kz + (size_t)b * NT * TILB;
    const char* VzB = (const char*)Vz + (size_t)b * NT * TILB;

    // group-private DMA: each of the 2 qslot waves stages 4KB K + 4KB V
    auto DMA = [&](int buf, int t) {
        const char* ks = KzB + (size_t)t * TILB;
        const char* vs = VzB + (size_t)t * TILB;
        char* dst = &lds[grp * 32768 + buf * 16384];
        const int off = qslot * 4096;
        #pragma unroll
        for (int j = 0; j < 4; ++j) {
            __builtin_amdgcn_global_load_lds(
                (const __attribute__((address_space(1))) u32*)(ks + off + j * 1024 + lane * 16),
                (__attribute__((address_space(3))) u32*)(dst + off + j * 1024), 16, 0, 0);
            __builtin_amdgcn_global_load_lds(
                (const __attribute__((address_space(1))) u32*)(vs + off + j * 1024 + lane * 16),
                (__attribute__((address_space(3))) u32*)(dst + 8192 + off + j * 1024), 16, 0, 0);
        }
    };

    f32x4 Oacc0[8], Oacc1[8];
    #pragma unroll
    for (int dg = 0; dg < 8; ++dg) { Oacc0[dg] = 0.f; Oacc1[dg] = 0.f; }
    float ll0 = 0.f, ll1 = 0.f;
    const int lb = lane * 16;

    // ---- prologue: each group stages its first tile ----
    if (grp < nt) DMA(0, grp);
    __syncthreads();

    int cur = 0;
    #pragma unroll 1
    for (int i = 0; i < IT; ++i) {
        const int t  = grp + i * NGRP;
        const int tn = t + NGRP;
        if (tn < nt) DMA(cur ^ 1, tn);   // T3: issue next, drained at end-of-iter sync

        if (t < nt) {
            const char* ksb = &lds[grp * 32768 + cur * 16384];
            const char* vsb = ksb + 8192;

            // ---- S^T = K * Q^T : one kf read feeds both q-streams ----
            f32x4 Sa0[2], Sa1[2];
            Sa0[0] = 0.f; Sa0[1] = 0.f; Sa1[0] = 0.f; Sa1[1] = 0.f;
            __builtin_amdgcn_s_setprio(1);
            #pragma unroll
            for (int s = 0; s < 2; ++s)
                #pragma unroll
                for (int kk = 0; kk < 4; ++kk) {
                    s16x8 kf = *reinterpret_cast<const s16x8*>(ksb + (s * 4 + kk) * 1024 + lb);
                    Sa0[s] = __builtin_amdgcn_mfma_f32_16x16x32_bf16(kf, qf0[kk], Sa0[s], 0, 0, 0);
                    Sa1[s] = __builtin_amdgcn_mfma_f32_16x16x32_bf16(kf, qf1[kk], Sa1[s], 0, 0, 0);
                }
            __builtin_amdgcn_s_setprio(0);

            // ---- valid_length mask (tail tile only) ----
            const int kvrem = vl - t * KVB;
            if (kvrem < KVB) {
                #pragma unroll
                for (int s = 0; s < 2; ++s)
                    #pragma unroll
                    for (int r = 0; r < 4; ++r)
                        if (s * 16 + gl * 4 + r >= kvrem) { Sa0[s][r] = -1e30f; Sa1[s][r] = -1e30f; }
            }

            // ---- fixed-origin softmax numerators ----
            s16x8 pa0, pa1;
            #pragma unroll
            for (int s = 0; s < 2; ++s)
                #pragma unroll
                for (int r = 0; r < 4; ++r) {
                    const float e0 = __builtin_amdgcn_exp2f(fminf(Sa0[s][r], 60.f));
                    const float e1 = __builtin_amdgcn_exp2f(fminf(Sa1[s][r], 60.f));
                    ll0 += e0; ll1 += e1;
                    pa0[s * 4 + r] = f2bf(e0);
                    pa1[s * 4 + r] = f2bf(e1);
                }

            // ---- O += P * V : one vf read feeds both q-streams ----
            __builtin_amdgcn_s_setprio(1);
            #pragma unroll
            for (int dg = 0; dg < 8; ++dg) {
                s16x8 vf = *reinterpret_cast<const s16x8*>(vsb + dg * 1024 + lb);
                Oacc0[dg] = __builtin_amdgcn_mfma_f32_16x16x32_bf16(pa0, vf, Oacc0[dg], 0, 0, 0);
                Oacc1[dg] = __builtin_amdgcn_mfma_f32_16x16x32_bf16(pa1, vf, Oacc1[dg], 0, 0, 0);
            }
            __builtin_amdgcn_s_setprio(0);
        }

        __syncthreads();   // uniform across all 8 waves; frees buf, drains DMA
        cur ^= 1;
    }

    // ---- l reduction across the 4 replicated gl groups ----
    ll0 += __shfl_xor(ll0, 16); ll0 += __shfl_xor(ll0, 32);
    ll1 += __shfl_xor(ll1, 16); ll1 += __shfl_xor(ll1, 32);

    // ---- parallel merge (R19): partials f32x4-contiguous, 4 virtual qslots ----
    float* P    = (float*)lds;                 // [(grp*4+vq)*8+dg][lane] f32x4
    float* lred = (float*)&lds[131072];        // [grp*64 + vq*16 + qi]
    const int vq0 = qslot * 2, vq1 = vq0 + 1;
    {
        float* w0 = P + (((size_t)(grp * 4 + vq0)) * 8) * 256;
        float* w1 = P + (((size_t)(grp * 4 + vq1)) * 8) * 256;
        #pragma unroll
        for (int dg = 0; dg < 8; ++dg) {
            *reinterpret_cast<f32x4*>(w0 + dg * 256 + lane * 4) = Oacc0[dg];
            *reinterpret_cast<f32x4*>(w1 + dg * 256 + lane * 4) = Oacc1[dg];
        }
        if (gl == 0) {
            lred[grp * 64 + vq0 * 16 + qi] = ll0;
            lred[grp * 64 + vq1 * 16 + qi] = ll1;
        }
    }
    __syncthreads();

    // each wave merges + writes its 2 vq slots x dg in {2*grp, 2*grp+1}
    #pragma unroll
    for (int h = 0; h < 2; ++h) {
        const int vq = qslot * 2 + h;
        float ltot = 0.f;
        #pragma unroll
        for (int g2 = 0; g2 < 4; ++g2) ltot += lred[g2 * 64 + vq * 16 + qi];
        const float linv = 1.0f / ltot;
        const float l0 = __shfl(linv, gl * 4 + 0);
        const float l1 = __shfl(linv, gl * 4 + 1);
        const float l2 = __shfl(linv, gl * 4 + 2);
        const float l3 = __shfl(linv, gl * 4 + 3);

        float* Ob = O + (size_t)(b * n + qt * BLKQ + vq * 16) * DHEAD;
        #pragma unroll
        for (int k = 0; k < 2; ++k) {
            const int dg = grp * 2 + k;
            f32x4 acc = 0.f;
            #pragma unroll
            for (int g2 = 0; g2 < 4; ++g2) {
                const float* rp = P + (((size_t)(g2 * 4 + vq)) * 8 + dg) * 256 + lane * 4;
                f32x4 v = *reinterpret_cast<const f32x4*>(rp);
                acc[0] += v[0]; acc[1] += v[1]; acc[2] += v[2]; acc[3] += v[3];
            }
            Ob[(gl * 4 + 0) * DHEAD + dg * 16 + qi] = acc[0] * l0;
            Ob[(gl * 4 + 1) * DHEAD + dg * 16 + qi] = acc[1] * l1;
            Ob[(gl * 4 + 2) * DHEAD + dg * 16 + qi] = acc[2] * l2;
            Ob[(gl * 4 + 3) * DHEAD + dg * 16 + qi] = acc[3] * l3;
        }
    }
}

extern "C" void kernel_launch(void* const* d_in, const int* in_sizes, int n_in,
                              void* d_out, int out_size, void* d_ws, size_t ws_size,
                              hipStream_t stream) {
    const float* Q  = (const float*)d_in[0];
    const float* K  = (const float*)d_in[1];
    const float* V  = (const float*)d_in[2];
    const int*   VL = (const int*)d_in[3];
    float* O = (float*)d_out;

    const int B = in_sizes[3];
    const int n = in_sizes[0] / (B * DHEAD);
    const int m = in_sizes[1] / (B * DHEAD);
    const int NT = m / KVB;                     // 32

    short* Kz = (short*)d_ws;
    short* Vz = Kz + (size_t)B * NT * (TILB / 2);

    const int nkf = B * NT * 512;               // s16x8 units per tensor
    prep_frag<<<(2 * nkf + 255) / 256, 256, 0, stream>>>(K, V, VL, Kz, Vz, m, NT, nkf);

    hipFuncSetAttribute((const void*)attn_fwd,
                        hipFuncAttributeMaxDynamicSharedMemorySize, LDSZ);
    const int grid = B * (n / BLKQ);            // 256
    attn_fwd<<<grid, 512, LDSZ, stream>>>(Q, Kz, Vz, VL, O, B, n, NT);
}